// Round 13
// baseline (365.363 us; speedup 1.0000x reference)
//
#include <hip/hip_runtime.h>
#include <hip/hip_bf16.h>

#define DEV __device__ __forceinline__

typedef __attribute__((ext_vector_type(4))) float f32x4;
typedef __attribute__((ext_vector_type(8))) short bf8_t;    // 8 bf16 = 4 VGPR
typedef __attribute__((ext_vector_type(4))) unsigned int u32x4;

static constexpr float QSCALE = 0.125f;   // dh^-0.5, dh=64

DEV float bflo(unsigned int w){ union{unsigned int i; float f;} x; x.i = w << 16; return x.f; }
DEV float bfhi(unsigned int w){ union{unsigned int i; float f;} x; x.i = w & 0xffff0000u; return x.f; }
DEV float bf2f(unsigned short u){ union{unsigned int i; float f;} x; x.i = ((unsigned int)u) << 16; return x.f; }
DEV unsigned short f2bf(float f){
  union{float f; unsigned int i;} x; x.f = f;
  unsigned int i = x.i;
  i += 0x7fffu + ((i >> 16) & 1u);   // round-to-nearest-even
  return (unsigned short)(i >> 16);
}
DEV unsigned int pack2(float a, float b){ return (unsigned int)f2bf(a) | ((unsigned int)f2bf(b) << 16); }

DEV void mfma_acc(f32x4& c, const bf8_t& a, const bf8_t& b){
  asm volatile("v_mfma_f32_16x16x32_bf16 %0, %1, %2, %0" : "+v"(c) : "v"(a), "v"(b));
}

// async global->LDS 16B per lane: dst = wave-uniform base + lane*16
DEV void cp16(unsigned short* l, const unsigned short* g){
  __builtin_amdgcn_global_load_lds(
      (const __attribute__((address_space(1))) unsigned int*)(const void*)g,
      (__attribute__((address_space(3))) unsigned int*)(void*)l, 16, 0, 0);
}

DEV float wred_max(float v){
  #pragma unroll
  for (int m = 1; m < 64; m <<= 1) v = fmaxf(v, __shfl_xor(v, m));
  return v;
}
DEV float wred_sum(float v){
  #pragma unroll
  for (int m = 1; m < 64; m <<= 1) v += __shfl_xor(v, m);
  return v;
}

// ---------------- fused: x->bf16 convert (blocks 0..2047) + weight prep (2048..2559) ----------------
__global__ void k_prep_cvt(const float* __restrict__ x, unsigned short* __restrict__ xb,
                           const float* __restrict__ qw, const float* __restrict__ kvw,
                           const float* __restrict__ pw, const float* __restrict__ qb,
                           const float* __restrict__ kvb,
                           unsigned short* __restrict__ wqkvt, unsigned short* __restrict__ wprojt,
                           float* __restrict__ qkvbias){
  if (blockIdx.x < 2048){
    const long total8 = (long)50176*512/8;
    const long stride = (long)2048*256;
    for (long i = (long)blockIdx.x*256 + threadIdx.x; i < total8; i += stride){
      const float4* p = (const float4*)(x + i*8);
      float4 a = p[0], b = p[1];
      u32x4 o;
      o.x = pack2(a.x, a.y); o.y = pack2(a.z, a.w);
      o.z = pack2(b.x, b.y); o.w = pack2(b.z, b.w);
      *(u32x4*)(xb + i*8) = o;
    }
  } else {
    const int i0 = (blockIdx.x - 2048) * 256 + threadIdx.x;
    const int stride = 512 * 256;
    for (int idx = i0; idx < 1536*512; idx += stride){
      int n = idx >> 9, k = idx & 511;
      float v = (n < 512) ? qw[k*512 + n] : kvw[k*1024 + (n - 512)];
      wqkvt[idx] = f2bf(v);                      // wqkvt[n][k]
    }
    for (int idx = i0; idx < 512*512; idx += stride){
      int n = idx >> 9, k = idx & 511;
      wprojt[idx] = f2bf(pw[k*512 + n]);         // wprojt[n][k]
    }
    for (int idx = i0; idx < 1536; idx += stride)
      qkvbias[idx] = (idx < 512) ? qb[idx] : kvb[idx - 512];
  }
}

// ---------------- GEMM: C[M,N] = A[M,512] * Bt[N,512]^T + bias ----------------
// m97-structure, BK=64, 128B LDS rows, both-sides XOR slot-swizzle.
template<bool OUT_BF>
__global__ __launch_bounds__(256) void k_gemm(const unsigned short* __restrict__ A,
    const unsigned short* __restrict__ Bt, const float* __restrict__ bias,
    void* __restrict__ Cp, const int N, const int nxb){
  __shared__ unsigned short Al[128][64];   // 16 KB
  __shared__ unsigned short Bl[128][64];   // 16 KB
  const int tid = threadIdx.x, lane = tid & 63, w = tid >> 6;
  const int bid = blockIdx.x;
  const int cxd = bid & 7, kk = bid >> 3;
  const int yi = kk / nxb, xb = kk - yi*nxb;
  const int m0 = (cxd + 8*yi) * 128, n0 = xb * 128;
  const int wr = (w >> 1) * 64, wc = (w & 1) * 64;
  const int fr = lane & 15, kg = lane >> 4;

  const int lr = lane >> 3, slog = (lane & 7) ^ lr;
  const unsigned short* gA = A  + (size_t)(m0 + w*32 + lr)*512 + slog*8;
  const unsigned short* gB = Bt + (size_t)(n0 + w*32 + lr)*512 + slog*8;

  f32x4 acc[4][4] = {};
  for (int kt = 0; kt < 8; ++kt){
    const int k0 = kt * 64;
    __syncthreads();
    #pragma unroll
    for (int cch = 0; cch < 4; ++cch){
      cp16(&Al[w*32 + cch*8][0], gA + (size_t)cch*8*512 + k0);
      cp16(&Bl[w*32 + cch*8][0], gB + (size_t)cch*8*512 + k0);
    }
    __syncthreads();
    bf8_t afl[4], afh[4];
    #pragma unroll
    for (int i = 0; i < 4; ++i){
      const int row = wr + i*16 + fr;
      const int sl = (kg ^ (row & 7)) * 8;
      afl[i] = *(const bf8_t*)&Al[row][sl];
      afh[i] = *(const bf8_t*)&Al[row][sl ^ 32];
    }
    #pragma unroll
    for (int j = 0; j < 4; ++j){
      const int row = wc + j*16 + fr;
      const int sl = (kg ^ (row & 7)) * 8;
      bf8_t bfl = *(const bf8_t*)&Bl[row][sl];
      bf8_t bfh = *(const bf8_t*)&Bl[row][sl ^ 32];
      #pragma unroll
      for (int i = 0; i < 4; ++i){
        mfma_acc(acc[i][j], afl[i], bfl);
        mfma_acc(acc[i][j], afh[i], bfh);
      }
    }
  }
  const int rb = kg * 4;
  #pragma unroll
  for (int j = 0; j < 4; ++j){
    const int col = n0 + wc + j*16 + fr;
    const float bs = bias[col];
    #pragma unroll
    for (int i = 0; i < 4; ++i){
      #pragma unroll
      for (int r = 0; r < 4; ++r){
        const int row = m0 + wr + i*16 + rb + r;
        float v = acc[i][j][r] + bs;
        if (OUT_BF) ((unsigned short*)Cp)[(size_t)row*N + col] = f2bf(v);
        else        ((float*)Cp)[(size_t)row*N + col] = v;
      }
    }
  }
}

// ---------------- bilinear 7->56 helper ----------------
DEV void lin_w(int o, int& i0, int& i1, float& w){
  float src = (o + 0.5f)*0.125f - 0.5f;
  src = fmaxf(src, 0.f);
  int f = (int)floorf(src);
  i0 = min(f, 6); i1 = min(i0 + 1, 6); w = src - (float)i0;
}

// ---------------- fused: agent pooling (blocks 0..783) + bias builder (784..1807) ----------------
__global__ void k_pool_bias(const unsigned short* __restrict__ qkv, float* __restrict__ agent,
                            const float* __restrict__ an, const float* __restrict__ ahb,
                            const float* __restrict__ awb,
                            const float* __restrict__ na, const float* __restrict__ hab,
                            const float* __restrict__ wab,
                            float* __restrict__ pbs, float* __restrict__ absumP){
  if (blockIdx.x < 784){
    const int b = blockIdx.x / 49, a = blockIdx.x % 49;
    const int p1 = a / 7, p2 = a % 7;
    const int c0 = threadIdx.x * 2;
    float s0 = 0.f, s1 = 0.f;
    const unsigned short* base = qkv + (size_t)b*3136*1536 + c0;
    for (int r = 0; r < 8; ++r)
      #pragma unroll
      for (int cc = 0; cc < 8; ++cc){
        int pix = (p1*8 + r)*56 + p2*8 + cc;
        unsigned int v = *(const unsigned int*)(base + (size_t)pix*1536);
        s0 += bflo(v); s1 += bfhi(v);
      }
    float* dst = agent + ((size_t)b*49 + a)*512 + c0;
    dst[0] = s0 * (1.0f/64.0f);
    dst[1] = s1 * (1.0f/64.0f);
  } else {
    const int i0 = (blockIdx.x - 784) * 256 + threadIdx.x;
    const int stride = 1024 * 256;
    const int tot1 = 8*49*3136;
    for (int idx = i0; idx < tot1; idx += stride){
      int n = idx % 3136, ha = idx / 3136;
      int y = n / 56, x = n % 56;
      int iy0, iy1, ix0, ix1; float wy, wx;
      lin_w(y, iy0, iy1, wy); lin_w(x, ix0, ix1, wx);
      const float* t = an + (size_t)ha*49;
      float v0 = t[iy0*7+ix0]*(1.f-wy) + t[iy1*7+ix0]*wy;
      float v1 = t[iy0*7+ix1]*(1.f-wy) + t[iy1*7+ix1]*wy;
      float v = v0*(1.f-wx) + v1*wx;
      pbs[idx] = v + ahb[ha*56 + y] + awb[ha*56 + x];
    }
    const int tot2 = 8*3136*64;
    for (int idx = i0; idx < tot2; idx += stride){
      int a = idx & 63, hn = idx >> 6;
      int n = hn % 3136, h = hn / 3136;
      float out = 0.f;
      if (a < 49){
        int y = n / 56, x = n % 56;
        int iy0, iy1, ix0, ix1; float wy, wx;
        lin_w(y, iy0, iy1, wy); lin_w(x, ix0, ix1, wx);
        const float* t = na + (size_t)(h*49 + a)*49;
        float v0 = t[iy0*7+ix0]*(1.f-wy) + t[iy1*7+ix0]*wy;
        float v1 = t[iy0*7+ix1]*(1.f-wy) + t[iy1*7+ix1]*wy;
        float v = v0*(1.f-wx) + v1*wx;
        out = v + hab[(h*56+y)*49 + a] + wab[(h*56+x)*49 + a];
      }
      absumP[idx] = out;
    }
  }
}

// ---------------- s1: agent attention via MFMA, flash over n, split 7 ----------------
// XCD-grouped by head: XCD = bi&7 = h.
__global__ __launch_bounds__(256) void k_attn1(const unsigned short* __restrict__ qkv,
    const float* __restrict__ agent, const float* __restrict__ pbs,
    float* __restrict__ pacc, float* __restrict__ pml){
  const int bi = blockIdx.x;
  const int h = bi & 7, rest = bi >> 3;     // 112 = 16b x 7sp per head
  const int b = rest / 7, sp = rest % 7;
  const int tid = threadIdx.x, lane = tid & 63, w = tid >> 6;
  const int c = lane & 15, kg = lane >> 4;

  __shared__ unsigned short ag[64][72];
  __shared__ unsigned short Kl[64][64];     // linear, XOR slot-swizzled
  __shared__ unsigned short Vt[64][72];
  __shared__ unsigned short Pl[4][16][72];

  for (int it = tid; it < 64*8; it += 256){
    int a = it >> 3, o = it & 7;
    u32x4 wv = {0,0,0,0};
    if (a < 49){
      const float* p = agent + ((size_t)b*49 + a)*512 + h*64 + o*8;
      f32x4 lo = *(const f32x4*)p, hi = *(const f32x4*)(p+4);
      wv.x = pack2(lo.x*QSCALE, lo.y*QSCALE);
      wv.y = pack2(lo.z*QSCALE, lo.w*QSCALE);
      wv.z = pack2(hi.x*QSCALE, hi.y*QSCALE);
      wv.w = pack2(hi.z*QSCALE, hi.w*QSCALE);
    }
    *(u32x4*)&ag[a][o*8] = wv;
  }
  __syncthreads();
  bf8_t agf[2];
  agf[0] = *(const bf8_t*)&ag[w*16 + c][kg*8];
  agf[1] = *(const bf8_t*)&ag[w*16 + c][kg*8 + 32];

  const int aw = w*16 + c;
  const int amin = aw < 49 ? aw : 48;
  const bool areal = aw < 49;
  const float* pbrow = pbs + ((size_t)(h*49 + amin))*3136 + sp*448;

  // K cp16 source (pre-swizzled slots within 8-row chunks)
  const int lr = lane >> 3, slog = (lane & 7) ^ lr;
  const unsigned short* gK = qkv + ((size_t)b*3136 + sp*448 + w*16 + lr)*1536 + 512 + h*64 + slog*8;

  float m_ = -1e30f, l_ = 0.f;
  f32x4 acc[4] = {};

  for (int t = 0; t < 7; ++t){
    const int gn0 = sp*448 + t*64;
    f32x4 pb4[4];
    #pragma unroll
    for (int i = 0; i < 4; ++i)
      pb4[i] = *(const f32x4*)(pbrow + t*64 + 16*i + 4*kg);

    __syncthreads();
    cp16(&Kl[w*16][0],     gK + (size_t)t*64*1536);
    cp16(&Kl[w*16 + 8][0], gK + (size_t)(t*64 + 8)*1536);
    #pragma unroll
    for (int ii = 0; ii < 2; ++ii){
      const int o = w + ii*4;
      const unsigned short* vp = qkv + ((size_t)b*3136 + gn0 + lane)*1536 + 1024 + h*64 + o*8;
      u32x4 vv = *(const u32x4*)vp;
      unsigned int own[4] = {vv.x, vv.y, vv.z, vv.w};
      const int colbase = lane & ~1;
      const bool odd = lane & 1;
      #pragma unroll
      for (int q = 0; q < 4; ++q){
        unsigned int par = __shfl_xor(own[q], 1);
        unsigned int wv;
        int drow;
        if (!odd){ wv = (own[q] & 0xffffu) | (par << 16);          drow = o*8 + 2*q; }
        else     { wv = (par >> 16) | (own[q] & 0xffff0000u);      drow = o*8 + 2*q + 1; }
        *(unsigned int*)&Vt[drow][colbase] = wv;
      }
    }
    __syncthreads();

    f32x4 sa[4] = {};
    #pragma unroll
    for (int i = 0; i < 4; ++i){
      const int row = i*16 + c;
      const int sl = (kg ^ (row & 7)) * 8;
      bf8_t kf0 = *(const bf8_t*)&Kl[row][sl];
      bf8_t kf1 = *(const bf8_t*)&Kl[row][sl ^ 32];
      mfma_acc(sa[i], kf0, agf[0]);
      mfma_acc(sa[i], kf1, agf[1]);
    }

    float s16[4][4]; float mx = -1e30f;
    #pragma unroll
    for (int i = 0; i < 4; ++i)
      #pragma unroll
      for (int r = 0; r < 4; ++r){
        float sv = areal ? (sa[i][r] + pb4[i][r]) : -1e30f;
        s16[i][r] = sv; mx = fmaxf(mx, sv);
      }
    mx = fmaxf(mx, __shfl_xor(mx, 16));
    mx = fmaxf(mx, __shfl_xor(mx, 32));
    float mn = fmaxf(m_, mx);
    float al = __expf(m_ - mn);
    float rs = 0.f;
    #pragma unroll
    for (int i = 0; i < 4; ++i)
      #pragma unroll
      for (int r = 0; r < 4; ++r){
        float p = __expf(s16[i][r] - mn);
        s16[i][r] = p; rs += p;
      }
    rs += __shfl_xor(rs, 16);
    rs += __shfl_xor(rs, 32);
    m_ = mn; l_ = l_*al + rs;

    #pragma unroll
    for (int i = 0; i < 4; ++i){
      uint2 pw;
      pw.x = pack2(s16[i][0], s16[i][1]);
      pw.y = pack2(s16[i][2], s16[i][3]);
      *(uint2*)&Pl[w][c][16*i + 4*kg] = pw;
    }

    float al_s[4];
    #pragma unroll
    for (int r = 0; r < 4; ++r) al_s[r] = __shfl(al, 4*kg + r);
    #pragma unroll
    for (int j = 0; j < 4; ++j)
      #pragma unroll
      for (int r = 0; r < 4; ++r) acc[j][r] *= al_s[r];

    bf8_t pf0 = *(const bf8_t*)&Pl[w][c][kg*8];
    bf8_t pf1 = *(const bf8_t*)&Pl[w][c][kg*8 + 32];
    #pragma unroll
    for (int j = 0; j < 4; ++j){
      bf8_t vf0 = *(const bf8_t*)&Vt[j*16 + c][kg*8];
      bf8_t vf1 = *(const bf8_t*)&Vt[j*16 + c][kg*8 + 32];
      mfma_acc(acc[j], pf0, vf0);
      mfma_acc(acc[j], pf1, vf1);
    }
  }

  const int base = ((b*8 + h)*7 + sp)*49;
  #pragma unroll
  for (int r = 0; r < 4; ++r){
    const int a = w*16 + 4*kg + r;
    if (a < 49){
      float* dst = pacc + (size_t)(base + a)*64 + c;
      #pragma unroll
      for (int j = 0; j < 4; ++j) dst[16*j] = acc[j][r];
    }
  }
  if (kg == 0 && areal){
    pml[(base + aw)*2]     = m_;
    pml[(base + aw)*2 + 1] = l_;
  }
}

// ---------------- s2: q attention via MFMA (merge of 7 partials inlined) ----------------
// XCD-grouped by head: XCD = blk&7 = h; pacc/pml rows for a bh are L2-local.
__global__ __launch_bounds__(256) void k_attn2(const unsigned short* __restrict__ qkv,
    const float* __restrict__ agent, const float* __restrict__ pacc,
    const float* __restrict__ pml,
    const float* __restrict__ absumP, unsigned short* __restrict__ outb){
  const int blk = blockIdx.x;
  const int h = blk & 7, rest = blk >> 3;   // 208 = 16b x 13 per head
  const int b = rest / 13, tloc = rest % 13;
  const int bh = b*8 + h;
  const int tid = threadIdx.x, lane = tid & 63, w = tid >> 6;
  const int c = lane & 15, kg = lane >> 4;

  __shared__ unsigned short ag[64][72];
  __shared__ unsigned short avT[64][72];
  __shared__ unsigned short Pl[4][2][16][72];   // double-buffered by j-parity

  for (int it = tid; it < 64*8; it += 256){
    int a = it >> 3, o = it & 7;
    u32x4 wv = {0,0,0,0};
    if (a < 49){
      const float* p = agent + ((size_t)b*49 + a)*512 + h*64 + o*8;
      f32x4 lo = *(const f32x4*)p, hi = *(const f32x4*)(p+4);
      wv.x = pack2(lo.x*QSCALE, lo.y*QSCALE);
      wv.y = pack2(lo.z*QSCALE, lo.w*QSCALE);
      wv.z = pack2(hi.x*QSCALE, hi.y*QSCALE);
      wv.w = pack2(hi.z*QSCALE, hi.w*QSCALE);
    }
    *(u32x4*)&ag[a][o*8] = wv;
  }
  // inlined 7-way merge: avT[d][a] = (sum_s pacc_s * e_s) / (sum_s l_s * e_s)
  for (int it = tid; it < 64*64; it += 256){
    int a = it >> 6, d = it & 63;
    unsigned short outv = 0;
    if (a < 49){
      const int mbase = (bh*7)*49 + a;
      float ms[7], ls[7], M = -1e30f;
      #pragma unroll
      for (int s = 0; s < 7; ++s){
        ms[s] = pml[(mbase + s*49)*2];
        ls[s] = pml[(mbase + s*49)*2 + 1];
        M = fmaxf(M, ms[s]);
      }
      float L = 0.f, o = 0.f;
      #pragma unroll
      for (int s = 0; s < 7; ++s){
        float e = __expf(ms[s] - M);
        L += ls[s]*e;
        o += pacc[(size_t)(mbase + s*49)*64 + d]*e;
      }
      outv = f2bf(o / L);
    }
    avT[d][a] = outv;
  }
  __syncthreads();

  const int ti = tloc*4 + w;
  if (ti >= 49) return;
  const int pix0 = ti*64;

  bf8_t af[4][2];
  #pragma unroll
  for (int i = 0; i < 4; ++i){
    af[i][0] = *(const bf8_t*)&ag[i*16 + c][kg*8];
    af[i][1] = *(const bf8_t*)&ag[i*16 + c][kg*8 + 32];
  }

  for (int j = 0; j < 4; ++j){
    const int jb = j & 1;
    const int pix = pix0 + 16*j + c;
    const unsigned short* qp = qkv + ((size_t)b*3136 + pix)*1536 + h*64;
    bf8_t qf0 = *(const bf8_t*)(qp + kg*8);
    bf8_t qf1 = *(const bf8_t*)(qp + kg*8 + 32);
    f32x4 sa[4] = {};
    #pragma unroll
    for (int i = 0; i < 4; ++i){
      mfma_acc(sa[i], af[i][0], qf0);
      mfma_acc(sa[i], af[i][1], qf1);
    }
    const float* bp = absumP + ((size_t)h*3136 + pix)*64 + 4*kg;
    f32x4 bias4[4];
    #pragma unroll
    for (int i = 0; i < 4; ++i) bias4[i] = *(const f32x4*)(bp + 16*i);
    float s16[4][4]; float mx = -1e30f;
    #pragma unroll
    for (int i = 0; i < 4; ++i){
      #pragma unroll
      for (int r = 0; r < 4; ++r){
        int a = 16*i + 4*kg + r;
        float sv = (a < 49) ? (sa[i][r] + bias4[i][r]) : -1e30f;
        s16[i][r] = sv; mx = fmaxf(mx, sv);
      }
    }
    mx = fmaxf(mx, __shfl_xor(mx, 16));
    mx = fmaxf(mx, __shfl_xor(mx, 32));
    float rs = 0.f;
    #pragma unroll
    for (int i = 0; i < 4; ++i){
      #pragma unroll
      for (int r = 0; r < 4; ++r){
        float p = __expf(s16[i][r] - mx);
        s16[i][r] = p; rs += p;
      }
    }
    rs += __shfl_xor(rs, 16);
    rs += __shfl_xor(rs, 32);
    #pragma unroll
    for (int i = 0; i < 4; ++i){
      uint2 pw;
      pw.x = pack2(s16[i][0], s16[i][1]);
      pw.y = pack2(s16[i][2], s16[i][3]);
      *(uint2*)&Pl[w][jb][c][16*i + 4*kg] = pw;
    }
    bf8_t pf0 = *(const bf8_t*)&Pl[w][jb][c][kg*8];
    bf8_t pf1 = *(const bf8_t*)&Pl[w][jb][c][kg*8 + 32];
    f32x4 acc[4] = {};
    #pragma unroll
    for (int jd = 0; jd < 4; ++jd){
      bf8_t vf0 = *(const bf8_t*)&avT[jd*16 + c][kg*8];
      bf8_t vf1 = *(const bf8_t*)&avT[jd*16 + c][kg*8 + 32];
      mfma_acc(acc[jd], pf0, vf0);
      mfma_acc(acc[jd], pf1, vf1);
    }
    float l_s[4];
    #pragma unroll
    for (int r = 0; r < 4; ++r) l_s[r] = __shfl(rs, 4*kg + r);
    #pragma unroll
    for (int r = 0; r < 4; ++r){
      const int prow = pix0 + 16*j + 4*kg + r;
      unsigned short* op = outb + ((size_t)b*3136 + prow)*512 + h*64;
      float inv = 1.0f / l_s[r];
      #pragma unroll
      for (int jd = 0; jd < 4; ++jd)
        op[jd*16 + c] = f2bf(acc[jd][r] * inv);
    }
  }
}

// ---------------- depthwise 3x3 on v, RMW-add into outb ----------------
__global__ __launch_bounds__(256) void k_dwc(const unsigned short* __restrict__ qkv,
    const float* __restrict__ dwcw, const float* __restrict__ dwcb,
    unsigned short* __restrict__ outb){
  const int tid = threadIdx.x;
  const int oct = tid & 63, pxl = tid >> 6;
  const int bid = blockIdx.x;
  const int gp4 = (bid & 7) * 1568 + (bid >> 3);
  const int gp = gp4 * 4 + pxl;
  const int b = gp / 3136, pix = gp - b*3136;
  const int y = pix / 56, x = pix - y*56;
  const int c0 = oct * 8;

  f32x4 w4[18];
  const f32x4* wp = (const f32x4*)(dwcw + c0*9);
  #pragma unroll
  for (int i = 0; i < 18; ++i) w4[i] = wp[i];
  #define W(j,t) (w4[((j)*9+(t)) >> 2][((j)*9+(t)) & 3])

  float o[8];
  {
    f32x4 b0 = *(const f32x4*)(dwcb + c0);
    f32x4 b1 = *(const f32x4*)(dwcb + c0 + 4);
    o[0]=b0.x; o[1]=b0.y; o[2]=b0.z; o[3]=b0.w;
    o[4]=b1.x; o[5]=b1.y; o[6]=b1.z; o[7]=b1.w;
  }

  const unsigned short* vbase = qkv + (size_t)b*3136*1536 + 1024 + c0;
  #pragma unroll
  for (int ky = 0; ky < 3; ++ky){
    const int ny = y + ky - 1;
    if ((unsigned)ny >= 56u) continue;
    #pragma unroll
    for (int kx = 0; kx < 3; ++kx){
      const int nx = x + kx - 1;
      if ((unsigned)nx >= 56u) continue;
      u32x4 vv = *(const u32x4*)(vbase + (size_t)(ny*56 + nx)*1536);
      const int t = ky*3 + kx;
      o[0] += W(0,t)*bflo(vv.x); o[1] += W(1,t)*bfhi(vv.x);
      o[2] += W(2,t)*bflo(vv.y); o[3] += W(3,t)*bfhi(vv.y);
      o[4] += W(4,t)*bflo(vv.z); o[5] += W(5,t)*bfhi(vv.z);
      o[6] += W(6,t)*bflo(vv.w); o[7] += W(7,t)*bfhi(vv.w);
    }
  }
  #undef W

  unsigned short* op = outb + (size_t)gp*512 + c0;
  u32x4 a = *(u32x4*)op;
  o[0] += bflo(a.x); o[1] += bfhi(a.x);
  o[2] += bflo(a.y); o[3] += bfhi(a.y);
  o[4] += bflo(a.z); o[5] += bfhi(a.z);
  o[6] += bflo(a.w); o[7] += bfhi(a.w);
  u32x4 r;
  r.x = pack2(o[0], o[1]); r.y = pack2(o[2], o[3]);
  r.z = pack2(o[4], o[5]); r.w = pack2(o[6], o[7]);
  *(u32x4*)op = r;
}

extern "C" void kernel_launch(void* const* d_in, const int* in_sizes, int n_in,
                              void* d_out, int out_size, void* d_ws, size_t ws_size,
                              hipStream_t stream){
  const float* x       = (const float*)d_in[0];
  const float* q_w     = (const float*)d_in[3];
  const float* q_b     = (const float*)d_in[4];
  const float* kv_w    = (const float*)d_in[5];
  const float* kv_b    = (const float*)d_in[6];
  const float* proj_w  = (const float*)d_in[7];
  const float* proj_b  = (const float*)d_in[8];
  const float* dwc_w   = (const float*)d_in[9];
  const float* dwc_b   = (const float*)d_in[10];
  const float* an_bias = (const float*)d_in[11];
  const float* na_bias = (const float*)d_in[12];
  const float* ah_bias = (const float*)d_in[13];
  const float* aw_bias = (const float*)d_in[14];
  const float* ha_bias = (const float*)d_in[15];
  const float* wa_bias = (const float*)d_in[16];

  char* ws = (char*)d_ws;
  size_t off = 0;
  auto alloc = [&](size_t bytes) -> void* {
    void* p = ws + off;
    off += (bytes + 255) & ~(size_t)255;
    return p;
  };
  unsigned short* xb     = (unsigned short*)alloc((size_t)50176*512*2);
  unsigned short* qkv    = (unsigned short*)alloc((size_t)50176*1536*2);
  unsigned short* wqkvt  = (unsigned short*)alloc((size_t)1536*512*2);
  unsigned short* wprojt = (unsigned short*)alloc((size_t)512*512*2);
  float* qkvb   = (float*)alloc((size_t)1536*4);
  float* agent  = (float*)alloc((size_t)16*49*512*4);
  float* pbs    = (float*)alloc((size_t)8*49*3136*4);
  float* absumP = (float*)alloc((size_t)8*3136*64*4);
  float* pacc   = (float*)alloc((size_t)16*8*8*49*64*4);
  float* pml    = (float*)alloc((size_t)16*8*8*49*2*4);
  unsigned short* outb = (unsigned short*)alloc((size_t)50176*512*2);
  if (off > ws_size) return;

  k_prep_cvt<<<2560, 256, 0, stream>>>(x, xb, q_w, kv_w, proj_w, q_b, kv_b, wqkvt, wprojt, qkvb);
  k_gemm<true><<<4704, 256, 0, stream>>>(xb, wqkvt, qkvb, qkv, 1536, 12);
  k_pool_bias<<<1808, 256, 0, stream>>>(qkv, agent, an_bias, ah_bias, aw_bias, na_bias, ha_bias, wa_bias, pbs, absumP);
  k_attn1<<<896, 256, 0, stream>>>(qkv, agent, pbs, pacc, pml);
  k_attn2<<<1664, 256, 0, stream>>>(qkv, agent, pacc, pml, absumP, outb);
  k_dwc<<<12544, 256, 0, stream>>>(qkv, dwc_w, dwc_b, outb);
  k_gemm<false><<<1568, 256, 0, stream>>>(outb, wprojt, proj_b, d_out, 512, 4);
}

// Round 14
// 350.313 us; speedup vs baseline: 1.0430x; 1.0430x over previous
//
#include <hip/hip_runtime.h>
#include <hip/hip_bf16.h>

#define DEV __device__ __forceinline__

typedef __attribute__((ext_vector_type(4))) float f32x4;
typedef __attribute__((ext_vector_type(8))) short bf8_t;    // 8 bf16 = 4 VGPR
typedef __attribute__((ext_vector_type(4))) unsigned int u32x4;

static constexpr float QSCALE = 0.125f;   // dh^-0.5, dh=64

DEV float bflo(unsigned int w){ union{unsigned int i; float f;} x; x.i = w << 16; return x.f; }
DEV float bfhi(unsigned int w){ union{unsigned int i; float f;} x; x.i = w & 0xffff0000u; return x.f; }
DEV float bf2f(unsigned short u){ union{unsigned int i; float f;} x; x.i = ((unsigned int)u) << 16; return x.f; }
DEV unsigned short f2bf(float f){
  union{float f; unsigned int i;} x; x.f = f;
  unsigned int i = x.i;
  i += 0x7fffu + ((i >> 16) & 1u);   // round-to-nearest-even
  return (unsigned short)(i >> 16);
}
DEV unsigned int pack2(float a, float b){ return (unsigned int)f2bf(a) | ((unsigned int)f2bf(b) << 16); }

DEV void mfma_acc(f32x4& c, const bf8_t& a, const bf8_t& b){
  asm volatile("v_mfma_f32_16x16x32_bf16 %0, %1, %2, %0" : "+v"(c) : "v"(a), "v"(b));
}

// async global->LDS 16B per lane: dst = wave-uniform base + lane*16
DEV void cp16(unsigned short* l, const unsigned short* g){
  __builtin_amdgcn_global_load_lds(
      (const __attribute__((address_space(1))) unsigned int*)(const void*)g,
      (__attribute__((address_space(3))) unsigned int*)(void*)l, 16, 0, 0);
}

DEV float wred_max(float v){
  #pragma unroll
  for (int m = 1; m < 64; m <<= 1) v = fmaxf(v, __shfl_xor(v, m));
  return v;
}
DEV float wred_sum(float v){
  #pragma unroll
  for (int m = 1; m < 64; m <<= 1) v += __shfl_xor(v, m);
  return v;
}

// ---------------- fused: x->bf16 convert (blocks 0..2047) + weight prep (2048..2559) ----------------
__global__ void k_prep_cvt(const float* __restrict__ x, unsigned short* __restrict__ xb,
                           const float* __restrict__ qw, const float* __restrict__ kvw,
                           const float* __restrict__ pw, const float* __restrict__ qb,
                           const float* __restrict__ kvb,
                           unsigned short* __restrict__ wqkvt, unsigned short* __restrict__ wprojt,
                           float* __restrict__ qkvbias){
  if (blockIdx.x < 2048){
    const long total8 = (long)50176*512/8;
    const long stride = (long)2048*256;
    for (long i = (long)blockIdx.x*256 + threadIdx.x; i < total8; i += stride){
      const float4* p = (const float4*)(x + i*8);
      float4 a = p[0], b = p[1];
      u32x4 o;
      o.x = pack2(a.x, a.y); o.y = pack2(a.z, a.w);
      o.z = pack2(b.x, b.y); o.w = pack2(b.z, b.w);
      *(u32x4*)(xb + i*8) = o;
    }
  } else {
    const int i0 = (blockIdx.x - 2048) * 256 + threadIdx.x;
    const int stride = 512 * 256;
    for (int idx = i0; idx < 1536*512; idx += stride){
      int n = idx >> 9, k = idx & 511;
      float v = (n < 512) ? qw[k*512 + n] : kvw[k*1024 + (n - 512)];
      wqkvt[idx] = f2bf(v);                      // wqkvt[n][k]
    }
    for (int idx = i0; idx < 512*512; idx += stride){
      int n = idx >> 9, k = idx & 511;
      wprojt[idx] = f2bf(pw[k*512 + n]);         // wprojt[n][k]
    }
    for (int idx = i0; idx < 1536; idx += stride)
      qkvbias[idx] = (idx < 512) ? qb[idx] : kvb[idx - 512];
  }
}

// ---------------- GEMM: C[M,N] = A[M,512] * Bt[N,512]^T + bias ----------------
// m97-structure, BK=64, 128B LDS rows, both-sides XOR slot-swizzle.
template<bool OUT_BF>
__global__ __launch_bounds__(256) void k_gemm(const unsigned short* __restrict__ A,
    const unsigned short* __restrict__ Bt, const float* __restrict__ bias,
    void* __restrict__ Cp, const int N, const int nxb){
  __shared__ unsigned short Al[128][64];   // 16 KB
  __shared__ unsigned short Bl[128][64];   // 16 KB
  const int tid = threadIdx.x, lane = tid & 63, w = tid >> 6;
  const int bid = blockIdx.x;
  const int cxd = bid & 7, kk = bid >> 3;
  const int yi = kk / nxb, xb = kk - yi*nxb;
  const int m0 = (cxd + 8*yi) * 128, n0 = xb * 128;
  const int wr = (w >> 1) * 64, wc = (w & 1) * 64;
  const int fr = lane & 15, kg = lane >> 4;

  const int lr = lane >> 3, slog = (lane & 7) ^ lr;
  const unsigned short* gA = A  + (size_t)(m0 + w*32 + lr)*512 + slog*8;
  const unsigned short* gB = Bt + (size_t)(n0 + w*32 + lr)*512 + slog*8;

  f32x4 acc[4][4] = {};
  for (int kt = 0; kt < 8; ++kt){
    const int k0 = kt * 64;
    __syncthreads();
    #pragma unroll
    for (int cch = 0; cch < 4; ++cch){
      cp16(&Al[w*32 + cch*8][0], gA + (size_t)cch*8*512 + k0);
      cp16(&Bl[w*32 + cch*8][0], gB + (size_t)cch*8*512 + k0);
    }
    __syncthreads();
    bf8_t afl[4], afh[4];
    #pragma unroll
    for (int i = 0; i < 4; ++i){
      const int row = wr + i*16 + fr;
      const int sl = (kg ^ (row & 7)) * 8;
      afl[i] = *(const bf8_t*)&Al[row][sl];
      afh[i] = *(const bf8_t*)&Al[row][sl ^ 32];
    }
    #pragma unroll
    for (int j = 0; j < 4; ++j){
      const int row = wc + j*16 + fr;
      const int sl = (kg ^ (row & 7)) * 8;
      bf8_t bfl = *(const bf8_t*)&Bl[row][sl];
      bf8_t bfh = *(const bf8_t*)&Bl[row][sl ^ 32];
      #pragma unroll
      for (int i = 0; i < 4; ++i){
        mfma_acc(acc[i][j], afl[i], bfl);
        mfma_acc(acc[i][j], afh[i], bfh);
      }
    }
  }
  const int rb = kg * 4;
  #pragma unroll
  for (int j = 0; j < 4; ++j){
    const int col = n0 + wc + j*16 + fr;
    const float bs = bias[col];
    #pragma unroll
    for (int i = 0; i < 4; ++i){
      #pragma unroll
      for (int r = 0; r < 4; ++r){
        const int row = m0 + wr + i*16 + rb + r;
        float v = acc[i][j][r] + bs;
        if (OUT_BF) ((unsigned short*)Cp)[(size_t)row*N + col] = f2bf(v);
        else        ((float*)Cp)[(size_t)row*N + col] = v;
      }
    }
  }
}

// ---------------- bilinear 7->56 helper ----------------
DEV void lin_w(int o, int& i0, int& i1, float& w){
  float src = (o + 0.5f)*0.125f - 0.5f;
  src = fmaxf(src, 0.f);
  int f = (int)floorf(src);
  i0 = min(f, 6); i1 = min(i0 + 1, 6); w = src - (float)i0;
}

// ---------------- fused: agent pooling (blocks 0..783) + bias builder (784..1807) ----------------
__global__ void k_pool_bias(const unsigned short* __restrict__ qkv, float* __restrict__ agent,
                            const float* __restrict__ an, const float* __restrict__ ahb,
                            const float* __restrict__ awb,
                            const float* __restrict__ na, const float* __restrict__ hab,
                            const float* __restrict__ wab,
                            float* __restrict__ pbs, float* __restrict__ absumP){
  if (blockIdx.x < 784){
    const int b = blockIdx.x / 49, a = blockIdx.x % 49;
    const int p1 = a / 7, p2 = a % 7;
    const int c0 = threadIdx.x * 2;
    float s0 = 0.f, s1 = 0.f;
    const unsigned short* base = qkv + (size_t)b*3136*1536 + c0;
    for (int r = 0; r < 8; ++r)
      #pragma unroll
      for (int cc = 0; cc < 8; ++cc){
        int pix = (p1*8 + r)*56 + p2*8 + cc;
        unsigned int v = *(const unsigned int*)(base + (size_t)pix*1536);
        s0 += bflo(v); s1 += bfhi(v);
      }
    float* dst = agent + ((size_t)b*49 + a)*512 + c0;
    dst[0] = s0 * (1.0f/64.0f);
    dst[1] = s1 * (1.0f/64.0f);
  } else {
    const int i0 = (blockIdx.x - 784) * 256 + threadIdx.x;
    const int stride = 1024 * 256;
    const int tot1 = 8*49*3136;
    for (int idx = i0; idx < tot1; idx += stride){
      int n = idx % 3136, ha = idx / 3136;
      int y = n / 56, x = n % 56;
      int iy0, iy1, ix0, ix1; float wy, wx;
      lin_w(y, iy0, iy1, wy); lin_w(x, ix0, ix1, wx);
      const float* t = an + (size_t)ha*49;
      float v0 = t[iy0*7+ix0]*(1.f-wy) + t[iy1*7+ix0]*wy;
      float v1 = t[iy0*7+ix1]*(1.f-wy) + t[iy1*7+ix1]*wy;
      float v = v0*(1.f-wx) + v1*wx;
      pbs[idx] = v + ahb[ha*56 + y] + awb[ha*56 + x];
    }
    const int tot2 = 8*3136*64;
    for (int idx = i0; idx < tot2; idx += stride){
      int a = idx & 63, hn = idx >> 6;
      int n = hn % 3136, h = hn / 3136;
      float out = 0.f;
      if (a < 49){
        int y = n / 56, x = n % 56;
        int iy0, iy1, ix0, ix1; float wy, wx;
        lin_w(y, iy0, iy1, wy); lin_w(x, ix0, ix1, wx);
        const float* t = na + (size_t)(h*49 + a)*49;
        float v0 = t[iy0*7+ix0]*(1.f-wy) + t[iy1*7+ix0]*wy;
        float v1 = t[iy0*7+ix1]*(1.f-wy) + t[iy1*7+ix1]*wy;
        float v = v0*(1.f-wx) + v1*wx;
        out = v + hab[(h*56+y)*49 + a] + wab[(h*56+x)*49 + a];
      }
      absumP[idx] = out;
    }
  }
}

// ---------------- s1: agent attention via MFMA, flash over n, split 7 ----------------
// XCD-grouped by head: XCD = bi&7 = h.
__global__ __launch_bounds__(256) void k_attn1(const unsigned short* __restrict__ qkv,
    const float* __restrict__ agent, const float* __restrict__ pbs,
    float* __restrict__ pacc, float* __restrict__ pml){
  const int bi = blockIdx.x;
  const int h = bi & 7, rest = bi >> 3;     // 112 = 16b x 7sp per head
  const int b = rest / 7, sp = rest % 7;
  const int tid = threadIdx.x, lane = tid & 63, w = tid >> 6;
  const int c = lane & 15, kg = lane >> 4;

  __shared__ unsigned short ag[64][72];
  __shared__ unsigned short Kl[64][64];     // linear, XOR slot-swizzled
  __shared__ unsigned short Vt[64][72];
  __shared__ unsigned short Pl[4][16][72];

  for (int it = tid; it < 64*8; it += 256){
    int a = it >> 3, o = it & 7;
    u32x4 wv = {0,0,0,0};
    if (a < 49){
      const float* p = agent + ((size_t)b*49 + a)*512 + h*64 + o*8;
      f32x4 lo = *(const f32x4*)p, hi = *(const f32x4*)(p+4);
      wv.x = pack2(lo.x*QSCALE, lo.y*QSCALE);
      wv.y = pack2(lo.z*QSCALE, lo.w*QSCALE);
      wv.z = pack2(hi.x*QSCALE, hi.y*QSCALE);
      wv.w = pack2(hi.z*QSCALE, hi.w*QSCALE);
    }
    *(u32x4*)&ag[a][o*8] = wv;
  }
  __syncthreads();
  bf8_t agf[2];
  agf[0] = *(const bf8_t*)&ag[w*16 + c][kg*8];
  agf[1] = *(const bf8_t*)&ag[w*16 + c][kg*8 + 32];

  const int aw = w*16 + c;
  const int amin = aw < 49 ? aw : 48;
  const bool areal = aw < 49;
  const float* pbrow = pbs + ((size_t)(h*49 + amin))*3136 + sp*448;

  // K cp16 source (pre-swizzled slots within 8-row chunks)
  const int lr = lane >> 3, slog = (lane & 7) ^ lr;
  const unsigned short* gK = qkv + ((size_t)b*3136 + sp*448 + w*16 + lr)*1536 + 512 + h*64 + slog*8;

  float m_ = -1e30f, l_ = 0.f;
  f32x4 acc[4] = {};

  for (int t = 0; t < 7; ++t){
    const int gn0 = sp*448 + t*64;
    f32x4 pb4[4];
    #pragma unroll
    for (int i = 0; i < 4; ++i)
      pb4[i] = *(const f32x4*)(pbrow + t*64 + 16*i + 4*kg);

    __syncthreads();
    cp16(&Kl[w*16][0],     gK + (size_t)t*64*1536);
    cp16(&Kl[w*16 + 8][0], gK + (size_t)(t*64 + 8)*1536);
    #pragma unroll
    for (int ii = 0; ii < 2; ++ii){
      const int o = w + ii*4;
      const unsigned short* vp = qkv + ((size_t)b*3136 + gn0 + lane)*1536 + 1024 + h*64 + o*8;
      u32x4 vv = *(const u32x4*)vp;
      unsigned int own[4] = {vv.x, vv.y, vv.z, vv.w};
      const int colbase = lane & ~1;
      const bool odd = lane & 1;
      #pragma unroll
      for (int q = 0; q < 4; ++q){
        unsigned int par = __shfl_xor(own[q], 1);
        unsigned int wv;
        int drow;
        if (!odd){ wv = (own[q] & 0xffffu) | (par << 16);          drow = o*8 + 2*q; }
        else     { wv = (par >> 16) | (own[q] & 0xffff0000u);      drow = o*8 + 2*q + 1; }
        *(unsigned int*)&Vt[drow][colbase] = wv;
      }
    }
    __syncthreads();

    f32x4 sa[4] = {};
    #pragma unroll
    for (int i = 0; i < 4; ++i){
      const int row = i*16 + c;
      const int sl = (kg ^ (row & 7)) * 8;
      bf8_t kf0 = *(const bf8_t*)&Kl[row][sl];
      bf8_t kf1 = *(const bf8_t*)&Kl[row][sl ^ 32];
      mfma_acc(sa[i], kf0, agf[0]);
      mfma_acc(sa[i], kf1, agf[1]);
    }

    float s16[4][4]; float mx = -1e30f;
    #pragma unroll
    for (int i = 0; i < 4; ++i)
      #pragma unroll
      for (int r = 0; r < 4; ++r){
        float sv = areal ? (sa[i][r] + pb4[i][r]) : -1e30f;
        s16[i][r] = sv; mx = fmaxf(mx, sv);
      }
    mx = fmaxf(mx, __shfl_xor(mx, 16));
    mx = fmaxf(mx, __shfl_xor(mx, 32));
    float mn = fmaxf(m_, mx);
    float al = __expf(m_ - mn);
    float rs = 0.f;
    #pragma unroll
    for (int i = 0; i < 4; ++i)
      #pragma unroll
      for (int r = 0; r < 4; ++r){
        float p = __expf(s16[i][r] - mn);
        s16[i][r] = p; rs += p;
      }
    rs += __shfl_xor(rs, 16);
    rs += __shfl_xor(rs, 32);
    m_ = mn; l_ = l_*al + rs;

    #pragma unroll
    for (int i = 0; i < 4; ++i){
      uint2 pw;
      pw.x = pack2(s16[i][0], s16[i][1]);
      pw.y = pack2(s16[i][2], s16[i][3]);
      *(uint2*)&Pl[w][c][16*i + 4*kg] = pw;
    }

    float al_s[4];
    #pragma unroll
    for (int r = 0; r < 4; ++r) al_s[r] = __shfl(al, 4*kg + r);
    #pragma unroll
    for (int j = 0; j < 4; ++j)
      #pragma unroll
      for (int r = 0; r < 4; ++r) acc[j][r] *= al_s[r];

    bf8_t pf0 = *(const bf8_t*)&Pl[w][c][kg*8];
    bf8_t pf1 = *(const bf8_t*)&Pl[w][c][kg*8 + 32];
    #pragma unroll
    for (int j = 0; j < 4; ++j){
      bf8_t vf0 = *(const bf8_t*)&Vt[j*16 + c][kg*8];
      bf8_t vf1 = *(const bf8_t*)&Vt[j*16 + c][kg*8 + 32];
      mfma_acc(acc[j], pf0, vf0);
      mfma_acc(acc[j], pf1, vf1);
    }
  }

  const int base = ((b*8 + h)*7 + sp)*49;
  #pragma unroll
  for (int r = 0; r < 4; ++r){
    const int a = w*16 + 4*kg + r;
    if (a < 49){
      float* dst = pacc + (size_t)(base + a)*64 + c;
      #pragma unroll
      for (int j = 0; j < 4; ++j) dst[16*j] = acc[j][r];
    }
  }
  if (kg == 0 && areal){
    pml[(base + aw)*2]     = m_;
    pml[(base + aw)*2 + 1] = l_;
  }
}

// ---------------- merge the 7 partial softmax states -> agent_v ----------------
__global__ void k_merge(const float* __restrict__ pacc, const float* __restrict__ pml,
                        float* __restrict__ agentv){
  const int gw = blockIdx.x*4 + (threadIdx.x >> 6);
  const int lane = threadIdx.x & 63;
  if (gw >= 16*8*49) return;
  const int a = gw % 49, bh = gw / 49;
  float ms[7], ls[7], M = -1e30f;
  #pragma unroll
  for (int s = 0; s < 7; ++s){
    int base = (bh*7 + s)*49 + a;
    ms[s] = pml[base*2]; ls[s] = pml[base*2 + 1];
    M = fmaxf(M, ms[s]);
  }
  float L = 0.f, o = 0.f;
  #pragma unroll
  for (int s = 0; s < 7; ++s){
    float e = __expf(ms[s] - M);
    L += ls[s]*e;
    o += pacc[(size_t)((bh*7 + s)*49 + a)*64 + lane]*e;
  }
  agentv[(size_t)(bh*49 + a)*64 + lane] = o / L;
}

// ---------------- s2: q attention via MFMA ----------------
// XCD-grouped by head: XCD = blk&7 = h, so absumP[h] (800 KB) stays in one L2.
__global__ __launch_bounds__(256) void k_attn2(const unsigned short* __restrict__ qkv,
    const float* __restrict__ agent, const float* __restrict__ agentv,
    const float* __restrict__ absumP, unsigned short* __restrict__ outb){
  const int blk = blockIdx.x;
  const int h = blk & 7, rest = blk >> 3;   // 208 = 16b x 13 per head
  const int b = rest / 13, tloc = rest % 13;
  const int bh = b*8 + h;
  const int tid = threadIdx.x, lane = tid & 63, w = tid >> 6;
  const int c = lane & 15, kg = lane >> 4;

  __shared__ unsigned short ag[64][72];
  __shared__ unsigned short avT[64][72];
  __shared__ unsigned short Pl[4][16][72];

  for (int it = tid; it < 64*8; it += 256){
    int a = it >> 3, o = it & 7;
    u32x4 wv = {0,0,0,0};
    if (a < 49){
      const float* p = agent + ((size_t)b*49 + a)*512 + h*64 + o*8;
      f32x4 lo = *(const f32x4*)p, hi = *(const f32x4*)(p+4);
      wv.x = pack2(lo.x*QSCALE, lo.y*QSCALE);
      wv.y = pack2(lo.z*QSCALE, lo.w*QSCALE);
      wv.z = pack2(hi.x*QSCALE, hi.y*QSCALE);
      wv.w = pack2(hi.z*QSCALE, hi.w*QSCALE);
    }
    *(u32x4*)&ag[a][o*8] = wv;
  }
  for (int it = tid; it < 64*64; it += 256){
    int a = it >> 6, d = it & 63;
    avT[d][a] = (a < 49) ? f2bf(agentv[((size_t)bh*49 + a)*64 + d]) : (unsigned short)0;
  }
  __syncthreads();

  const int ti = tloc*4 + w;
  if (ti >= 49) return;
  const int pix0 = ti*64;

  bf8_t af[4][2];
  #pragma unroll
  for (int i = 0; i < 4; ++i){
    af[i][0] = *(const bf8_t*)&ag[i*16 + c][kg*8];
    af[i][1] = *(const bf8_t*)&ag[i*16 + c][kg*8 + 32];
  }

  for (int j = 0; j < 4; ++j){
    const int pix = pix0 + 16*j + c;
    const unsigned short* qp = qkv + ((size_t)b*3136 + pix)*1536 + h*64;
    bf8_t qf0 = *(const bf8_t*)(qp + kg*8);
    bf8_t qf1 = *(const bf8_t*)(qp + kg*8 + 32);
    f32x4 sa[4] = {};
    #pragma unroll
    for (int i = 0; i < 4; ++i){
      mfma_acc(sa[i], af[i][0], qf0);
      mfma_acc(sa[i], af[i][1], qf1);
    }
    const float* bp = absumP + ((size_t)h*3136 + pix)*64 + 4*kg;
    f32x4 bias4[4];
    #pragma unroll
    for (int i = 0; i < 4; ++i) bias4[i] = *(const f32x4*)(bp + 16*i);
    float s16[4][4]; float mx = -1e30f;
    #pragma unroll
    for (int i = 0; i < 4; ++i){
      #pragma unroll
      for (int r = 0; r < 4; ++r){
        int a = 16*i + 4*kg + r;
        float sv = (a < 49) ? (sa[i][r] + bias4[i][r]) : -1e30f;
        s16[i][r] = sv; mx = fmaxf(mx, sv);
      }
    }
    mx = fmaxf(mx, __shfl_xor(mx, 16));
    mx = fmaxf(mx, __shfl_xor(mx, 32));
    float rs = 0.f;
    #pragma unroll
    for (int i = 0; i < 4; ++i){
      #pragma unroll
      for (int r = 0; r < 4; ++r){
        float p = __expf(s16[i][r] - mx);
        s16[i][r] = p; rs += p;
      }
    }
    rs += __shfl_xor(rs, 16);
    rs += __shfl_xor(rs, 32);
    #pragma unroll
    for (int i = 0; i < 4; ++i){
      uint2 pw;
      pw.x = pack2(s16[i][0], s16[i][1]);
      pw.y = pack2(s16[i][2], s16[i][3]);
      *(uint2*)&Pl[w][c][16*i + 4*kg] = pw;
    }
    bf8_t pf0 = *(const bf8_t*)&Pl[w][c][kg*8];
    bf8_t pf1 = *(const bf8_t*)&Pl[w][c][kg*8 + 32];
    f32x4 acc[4] = {};
    #pragma unroll
    for (int jd = 0; jd < 4; ++jd){
      bf8_t vf0 = *(const bf8_t*)&avT[jd*16 + c][kg*8];
      bf8_t vf1 = *(const bf8_t*)&avT[jd*16 + c][kg*8 + 32];
      mfma_acc(acc[jd], pf0, vf0);
      mfma_acc(acc[jd], pf1, vf1);
    }
    float l_s[4];
    #pragma unroll
    for (int r = 0; r < 4; ++r) l_s[r] = __shfl(rs, 4*kg + r);
    #pragma unroll
    for (int r = 0; r < 4; ++r){
      const int prow = pix0 + 16*j + 4*kg + r;
      unsigned short* op = outb + ((size_t)b*3136 + prow)*512 + h*64;
      float inv = 1.0f / l_s[r];
      #pragma unroll
      for (int jd = 0; jd < 4; ++jd)
        op[jd*16 + c] = f2bf(acc[jd][r] * inv);
    }
  }
}

// ---------------- depthwise 3x3 on v, RMW-add into outb ----------------
__global__ __launch_bounds__(256) void k_dwc(const unsigned short* __restrict__ qkv,
    const float* __restrict__ dwcw, const float* __restrict__ dwcb,
    unsigned short* __restrict__ outb){
  const int tid = threadIdx.x;
  const int oct = tid & 63, pxl = tid >> 6;
  const int bid = blockIdx.x;
  const int gp4 = (bid & 7) * 1568 + (bid >> 3);
  const int gp = gp4 * 4 + pxl;
  const int b = gp / 3136, pix = gp - b*3136;
  const int y = pix / 56, x = pix - y*56;
  const int c0 = oct * 8;

  f32x4 w4[18];
  const f32x4* wp = (const f32x4*)(dwcw + c0*9);
  #pragma unroll
  for (int i = 0; i < 18; ++i) w4[i] = wp[i];
  #define W(j,t) (w4[((j)*9+(t)) >> 2][((j)*9+(t)) & 3])

  float o[8];
  {
    f32x4 b0 = *(const f32x4*)(dwcb + c0);
    f32x4 b1 = *(const f32x4*)(dwcb + c0 + 4);
    o[0]=b0.x; o[1]=b0.y; o[2]=b0.z; o[3]=b0.w;
    o[4]=b1.x; o[5]=b1.y; o[6]=b1.z; o[7]=b1.w;
  }

  const unsigned short* vbase = qkv + (size_t)b*3136*1536 + 1024 + c0;
  #pragma unroll
  for (int ky = 0; ky < 3; ++ky){
    const int ny = y + ky - 1;
    if ((unsigned)ny >= 56u) continue;
    #pragma unroll
    for (int kx = 0; kx < 3; ++kx){
      const int nx = x + kx - 1;
      if ((unsigned)nx >= 56u) continue;
      u32x4 vv = *(const u32x4*)(vbase + (size_t)(ny*56 + nx)*1536);
      const int t = ky*3 + kx;
      o[0] += W(0,t)*bflo(vv.x); o[1] += W(1,t)*bfhi(vv.x);
      o[2] += W(2,t)*bflo(vv.y); o[3] += W(3,t)*bfhi(vv.y);
      o[4] += W(4,t)*bflo(vv.z); o[5] += W(5,t)*bfhi(vv.z);
      o[6] += W(6,t)*bflo(vv.w); o[7] += W(7,t)*bfhi(vv.w);
    }
  }
  #undef W

  unsigned short* op = outb + (size_t)gp*512 + c0;
  u32x4 a = *(u32x4*)op;
  o[0] += bflo(a.x); o[1] += bfhi(a.x);
  o[2] += bflo(a.y); o[3] += bfhi(a.y);
  o[4] += bflo(a.z); o[5] += bfhi(a.z);
  o[6] += bflo(a.w); o[7] += bfhi(a.w);
  u32x4 r;
  r.x = pack2(o[0], o[1]); r.y = pack2(o[2], o[3]);
  r.z = pack2(o[4], o[5]); r.w = pack2(o[6], o[7]);
  *(u32x4*)op = r;
}

extern "C" void kernel_launch(void* const* d_in, const int* in_sizes, int n_in,
                              void* d_out, int out_size, void* d_ws, size_t ws_size,
                              hipStream_t stream){
  const float* x       = (const float*)d_in[0];
  const float* q_w     = (const float*)d_in[3];
  const float* q_b     = (const float*)d_in[4];
  const float* kv_w    = (const float*)d_in[5];
  const float* kv_b    = (const float*)d_in[6];
  const float* proj_w  = (const float*)d_in[7];
  const float* proj_b  = (const float*)d_in[8];
  const float* dwc_w   = (const float*)d_in[9];
  const float* dwc_b   = (const float*)d_in[10];
  const float* an_bias = (const float*)d_in[11];
  const float* na_bias = (const float*)d_in[12];
  const float* ah_bias = (const float*)d_in[13];
  const float* aw_bias = (const float*)d_in[14];
  const float* ha_bias = (const float*)d_in[15];
  const float* wa_bias = (const float*)d_in[16];

  char* ws = (char*)d_ws;
  size_t off = 0;
  auto alloc = [&](size_t bytes) -> void* {
    void* p = ws + off;
    off += (bytes + 255) & ~(size_t)255;
    return p;
  };
  unsigned short* xb     = (unsigned short*)alloc((size_t)50176*512*2);
  unsigned short* qkv    = (unsigned short*)alloc((size_t)50176*1536*2);
  unsigned short* wqkvt  = (unsigned short*)alloc((size_t)1536*512*2);
  unsigned short* wprojt = (unsigned short*)alloc((size_t)512*512*2);
  float* qkvb   = (float*)alloc((size_t)1536*4);
  float* agent  = (float*)alloc((size_t)16*49*512*4);
  float* agentv = (float*)alloc((size_t)16*8*49*64*4);
  float* pbs    = (float*)alloc((size_t)8*49*3136*4);
  float* absumP = (float*)alloc((size_t)8*3136*64*4);
  float* pacc   = (float*)alloc((size_t)16*8*8*49*64*4);
  float* pml    = (float*)alloc((size_t)16*8*8*49*2*4);
  unsigned short* outb = (unsigned short*)alloc((size_t)50176*512*2);
  if (off > ws_size) return;

  k_prep_cvt<<<2560, 256, 0, stream>>>(x, xb, q_w, kv_w, proj_w, q_b, kv_b, wqkvt, wprojt, qkvb);
  k_gemm<true><<<4704, 256, 0, stream>>>(xb, wqkvt, qkvb, qkv, 1536, 12);
  k_pool_bias<<<1808, 256, 0, stream>>>(qkv, agent, an_bias, ah_bias, aw_bias, na_bias, ha_bias, wa_bias, pbs, absumP);
  k_attn1<<<896, 256, 0, stream>>>(qkv, agent, pbs, pacc, pml);
  k_merge<<<1568, 256, 0, stream>>>(pacc, pml, agentv);
  k_attn2<<<1664, 256, 0, stream>>>(qkv, agent, agentv, absumP, outb);
  k_dwc<<<12544, 256, 0, stream>>>(qkv, dwc_w, dwc_b, outb);
  k_gemm<false><<<1568, 256, 0, stream>>>(outb, wprojt, proj_b, d_out, 512, 4);
}